// Round 6
// baseline (516.117 us; speedup 1.0000x reference)
//
#include <hip/hip_runtime.h>
#include <stdint.h>

typedef unsigned short u16;
typedef uint32_t u32;
typedef short s16x8 __attribute__((ext_vector_type(8)));
typedef float fx16 __attribute__((ext_vector_type(16)));

#define B_   256
#define H_   1024
#define BH_  (B_ * H_)                  // 262144
#define WPE  ((size_t)2 * 4096 * 2048)  // W pack elems
#define WPAD 131072                     // guard for dummy pipeline stages
#define XPE  ((size_t)15 * BH_)
#define HPE  ((size_t)32 * BH_)

struct Stage { int node[8]; int par[8]; int layer[8]; int cnt; };

__device__ __forceinline__ u16 bf16_rn(float x) {
    union { float f; u32 u; } v; v.f = x;
    return (u16)((v.u + 0x7FFFu + ((v.u >> 16) & 1u)) >> 16);
}
__device__ __forceinline__ float sigf(float x) {
    return __builtin_amdgcn_rcpf(1.0f + __expf(-x));
}
__device__ __forceinline__ float tanh_f(float x) {
    return 1.0f - 2.0f * __builtin_amdgcn_rcpf(1.0f + __expf(2.0f * x));
}

// ---------------------------------------------------------------------------
// Pack W into MFMA-B fragment order, bf16. Chunk w = ((layer*4+gate)*32+cg)*128+k16;
// lane l -> W[gate*1024+cg*32+(l&31)][k16*16+(l>>5)*8+e].
// ---------------------------------------------------------------------------
__global__ __launch_bounds__(256)
void pack_weights(const float* __restrict__ Wih, const float* __restrict__ Whh,
                  u16* __restrict__ wp)
{
    const int gt = blockIdx.x * 256 + threadIdx.x;
    const int w = gt >> 6, lane = gt & 63;
    const int k16 = w & 127, cg = (w >> 7) & 31, gate = (w >> 12) & 3, layer = w >> 14;
    const int row = gate * 1024 + cg * 32 + (lane & 31);
    const int k = k16 * 16 + (lane >> 5) * 8;
    const float* src = (k < 1024)
        ? Wih + ((size_t)layer * 4096 + row) * 1024 + k
        : Whh + ((size_t)layer * 4096 + row) * 1024 + (k - 1024);
    const float4 v0 = *(const float4*)src;
    const float4 v1 = *(const float4*)(src + 4);
    const float a[8] = {v0.x, v0.y, v0.z, v0.w, v1.x, v1.y, v1.z, v1.w};
    union { u16 s[8]; uint4 v; } hi;
    #pragma unroll
    for (int e = 0; e < 8; ++e) hi.s[e] = bf16_rn(a[e]);
    *(uint4*)(wp + (size_t)w * 512 + (size_t)lane * 8) = hi.v;
}

__global__ __launch_bounds__(256)
void pack_x(const float* __restrict__ input, const float* __restrict__ bridge,
            u16* __restrict__ xp)
{
    const int gt = blockIdx.x * 256 + threadIdx.x;
    const int w = gt >> 6, lane = gt & 63;
    const int k16 = w & 63, btile = (w >> 6) & 7, n1 = w >> 9;
    const int b = btile * 32 + (lane & 31);
    const int k = k16 * 16 + (lane >> 5) * 8;
    const float* src = (k < 512)
        ? input  + ((size_t)n1 * 256 + b) * 512 + k
        : bridge + ((size_t)n1 * 256 + b) * 512 + (k - 512);
    const float4 v0 = *(const float4*)src;
    const float4 v1 = *(const float4*)(src + 4);
    const float a[8] = {v0.x, v0.y, v0.z, v0.w, v1.x, v1.y, v1.z, v1.w};
    union { u16 s[8]; uint4 v; } hi;
    #pragma unroll
    for (int e = 0; e < 8; ++e) hi.s[e] = bf16_rn(a[e]);
    *(uint4*)(xp + (size_t)w * 512 + (size_t)lane * 8) = hi.v;
}

__global__ __launch_bounds__(256)
void bias_sum_k(const float* __restrict__ bih, const float* __restrict__ bhh,
                float* __restrict__ bs)
{
    const int i = blockIdx.x * 256 + threadIdx.x;
    if (i < 8192) bs[i] = bih[i] + bhh[i];
}

// ---------------------------------------------------------------------------
// Fused cell. Block = 256 thr (4 waves, batch-stacked: wave wv owns batch
// rows 64*wv..64*wv+63). Block tile: 256 batch x 32 hh x 4 gates.
// Wave tile: 64 batch x 128 N -> acc[2][4] fx16 (128 VGPR), 8 MFMA per kk
// from 4 shared-W ds_reads (0.5 ds_read/MFMA) + 2 private-A global loads
// (register-direct from L2; A = 1MB/cell).
// W-only LDS ring: 3 x 16KB, staged via global_load_lds (4 x b128/thread).
// Schedule: vmcnt(12) [W(t) landed; W(t+1)+A(t-1) in flight] -> raw barrier
// -> stage W(t+2) -> compute(t).
// blocks/cell = 32 (hhblk); bid%8 = hhblk%8 -> stable XCD ownership of W.
// ---------------------------------------------------------------------------
__global__ __launch_bounds__(256, 2)
void cell_fused(const u16* __restrict__ wp, const u16* __restrict__ xp,
                u16* __restrict__ hp, float* __restrict__ c_buf,
                const float* __restrict__ bsum, float* __restrict__ out,
                Stage st)
{
    __shared__ u16 Wb[3][8192];    // 3 x 16 KB: [gate(4)][k16(4)][512]

    const int bid = blockIdx.x;
    const int cell = bid >> 5;
    const int hhblk = bid & 31;
    const int node = st.node[cell], par = st.par[cell], layer = st.layer[cell];
    const int tid = threadIdx.x, wv = tid >> 6, lane = tid & 63;
    const int bt0 = 2 * wv;

    // A segment bases (seg0 = K 0..1023, seg1 = K 1024..2047)
    const u16 *A0, *A1;
    if (layer == 0) {
        A0 = xp + (size_t)(node - 1) * BH_;
        A1 = hp + (size_t)(par * 2 + 0) * BH_;
    } else {
        A0 = hp + (size_t)(node * 2 + 0) * BH_;
        A1 = hp + (size_t)(par * 2 + 1) * BH_;
    }

    size_t wbase[4];
    #pragma unroll
    for (int g = 0; g < 4; ++g)
        wbase[g] = (size_t)((layer * 4 + g) * 32 + hhblk) * 65536;

    // stage 16KB W chunk for step T into ring buf S: 4 loads/thread (1/gate)
    #define STAGE(T, S) do {                                                   \
        _Pragma("unroll")                                                      \
        for (int g_ = 0; g_ < 4; ++g_) {                                       \
            __builtin_amdgcn_global_load_lds(                                  \
                (const __attribute__((address_space(1))) void*)                \
                    (wp + wbase[g_] + (size_t)(T) * 2048 + tid * 8),           \
                (__attribute__((address_space(3))) void*)                      \
                    (&Wb[S][g_ * 2048 + tid * 8]),                             \
                16, 0, 0);                                                     \
        }                                                                      \
    } while (0)

    #define COMPUTE(T, S) do {                                                 \
        const u16* As_ = ((T) < 16) ? A0 : A1;                                 \
        const size_t ab_ = ((size_t)bt0 * 64 + ((T) & 15) * 4) * 512           \
                         + (size_t)lane * 8;                                   \
        _Pragma("unroll")                                                      \
        for (int kk_ = 0; kk_ < 4; ++kk_) {                                    \
            const s16x8 a0_ = *(const s16x8*)(As_ + ab_ + kk_ * 512);          \
            const s16x8 a1_ = *(const s16x8*)(As_ + ab_ + 32768 + kk_ * 512);  \
            _Pragma("unroll")                                                  \
            for (int g_ = 0; g_ < 4; ++g_) {                                   \
                const s16x8 w_ = *(const s16x8*)                               \
                    (&Wb[S][g_ * 2048 + kk_ * 512 + lane * 8]);                \
                acc[0][g_] = __builtin_amdgcn_mfma_f32_32x32x16_bf16(          \
                    a0_, w_, acc[0][g_], 0, 0, 0);                             \
                acc[1][g_] = __builtin_amdgcn_mfma_f32_32x32x16_bf16(          \
                    a1_, w_, acc[1][g_], 0, 0, 0);                             \
            }                                                                  \
        }                                                                      \
    } while (0)

    fx16 acc[2][4];
    #pragma unroll
    for (int q = 0; q < 2; ++q)
        #pragma unroll
        for (int g = 0; g < 4; ++g)
            #pragma unroll
            for (int r = 0; r < 16; ++r) acc[q][g][r] = 0.0f;

    STAGE(0, 0);
    STAGE(1, 1);

    // t = 0 (peeled: only W(1) may remain in flight)
    asm volatile("s_waitcnt vmcnt(4)" ::: "memory");
    __builtin_amdgcn_s_barrier();
    STAGE(2, 2);
    COMPUTE(0, 0);

    #pragma unroll 1
    for (int t = 1; t < 32; ++t) {
        // W(t) guaranteed landed; W(t+1) + prev A loads may remain in flight
        asm volatile("s_waitcnt vmcnt(12)" ::: "memory");
        __builtin_amdgcn_s_barrier();
        const int s2 = (t + 2) % 3;          // t>=30 -> dummy stage into ring
        const int sT = (t + 2 < 32) ? (t + 2) : (t - 30);
        STAGE(sT, s2);
        COMPUTE(t, t % 3);
    }
    __syncthreads();   // drain dummies before LDS reuse

    // ---- fused gates epilogue (C/D: col=lane&31, row=(r&3)+8*(r>>2)+4*(lane>>5))
    const int col  = lane & 31;
    const int colg = hhblk * 32 + col;
    float bs4[4];
    #pragma unroll
    for (int g = 0; g < 4; ++g)
        bs4[g] = bsum[layer * 4096 + g * 1024 + colg];

    const float* cpar_base = c_buf + (size_t)(par * 2 + layer) * BH_ + colg;
    float*       cnew_base = c_buf + (size_t)(node * 2 + layer) * BH_ + colg;
    float*       out_base  = out + (size_t)(node - 1) * BH_ + colg;

    u32* hb = (u32*)(&Wb[0][0]);   // 8 quadrants x 32x33 u32 = 34.8KB < 48KB

    #pragma unroll
    for (int q = 0; q < 2; ++q) {
        const int bt = bt0 + q;
        u32* hq = hb + (wv * 2 + q) * 1088;
        #pragma unroll
        for (int r = 0; r < 16; ++r) {
            const int rl = 4 * (lane >> 5) + (r & 3) + 8 * (r >> 2);
            const size_t row = (size_t)(bt * 32 + rl) * 1024;
            const float gi = acc[q][0][r] + bs4[0];
            const float gf = acc[q][1][r] + bs4[1];
            const float gg = acc[q][2][r] + bs4[2];
            const float go = acc[q][3][r] + bs4[3];
            const float cp = cpar_base[row];
            const float cn = sigf(gf) * cp + sigf(gi) * tanh_f(gg);
            const float hn = sigf(go) * tanh_f(cn);
            cnew_base[row] = cn;
            if (layer == 1) out_base[row] = hn;
            hq[rl * 33 + col] = (u32)bf16_rn(hn);
        }
    }
    __syncthreads();

    // ---- transpose h (wave-local) into packed A-frag chunks for next cells
    #pragma unroll
    for (int q = 0; q < 2; ++q) {
        const int bt = bt0 + q;
        const u32* hq = hb + (wv * 2 + q) * 1088;
        #pragma unroll
        for (int h2 = 0; h2 < 2; ++h2) {
            union { u16 s[8]; uint4 v; } pk;
            #pragma unroll
            for (int e = 0; e < 8; ++e)
                pk.s[e] = (u16)hq[(lane & 31) * 33 + h2 * 16 + (lane >> 5) * 8 + e];
            *(uint4*)(hp + (size_t)(node * 2 + layer) * BH_
                      + ((size_t)bt * 64 + hhblk * 2 + h2) * 512 + lane * 8) = pk.v;
        }
    }
    #undef STAGE
    #undef COMPUTE
}

// ---------------------------------------------------------------------------
extern "C" void kernel_launch(void* const* d_in, const int* in_sizes, int n_in,
                              void* d_out, int out_size, void* d_ws, size_t ws_size,
                              hipStream_t stream)
{
    const float* input  = (const float*)d_in[0];
    const float* bridge = (const float*)d_in[1];
    const float* Wih    = (const float*)d_in[2];
    const float* Whh    = (const float*)d_in[3];
    const float* bih    = (const float*)d_in[4];
    const float* bhh    = (const float*)d_in[5];
    float* out = (float*)d_out;

    u16* wp = (u16*)d_ws;
    u16* xp = wp + WPE + WPAD;
    u16* hp = xp + XPE;
    float* c_buf = (float*)(hp + HPE);
    float* bsum  = c_buf + HPE;

    hipMemsetAsync(hp, 0, (size_t)2 * BH_ * sizeof(u16), stream);
    hipMemsetAsync(c_buf, 0, (size_t)2 * BH_ * sizeof(float), stream);

    bias_sum_k<<<32, 256, 0, stream>>>(bih, bhh, bsum);
    pack_weights<<<8192, 256, 0, stream>>>(Wih, Whh, wp);
    pack_x<<<1920, 256, 0, stream>>>(input, bridge, xp);

    // Wavefront schedule: stage T = cells (node,layer) with depth(node)+layer==T
    static const Stage stages[7] = {
        { {1},                      {0},                      {0},                      1 },
        { {1,2,5,8},                {0,1,1,1},                {1,0,0,0},                4 },
        { {2,5,8,3,6,9,12},         {1,1,1,2,5,8,8},          {1,1,1,0,0,0,0},          7 },
        { {3,6,9,12,4,7,10,13},     {2,5,8,8,3,6,9,12},       {1,1,1,1,0,0,0,0},        8 },
        { {4,7,10,13,11,14},        {3,6,9,12,10,13},         {1,1,1,1,0,0},            6 },
        { {11,14,15},               {10,13,14},               {1,1,0},                  3 },
        { {15},                     {14},                     {1},                      1 },
    };

    for (int s = 0; s < 7; ++s) {
        cell_fused<<<dim3(stages[s].cnt * 32), 256, 0, stream>>>(
            wp, xp, hp, c_buf, bsum, out, stages[s]);
    }
}

// Round 7
// 452.123 us; speedup vs baseline: 1.1415x; 1.1415x over previous
//
#include <hip/hip_runtime.h>
#include <stdint.h>

typedef unsigned short u16;
typedef uint32_t u32;
typedef short s16x8 __attribute__((ext_vector_type(8)));
typedef float fx16 __attribute__((ext_vector_type(16)));

#define B_   256
#define H_   1024
#define BH_  (B_ * H_)                  // 262144
#define WPE  ((size_t)2 * 4096 * 2048)  // W pack elems
#define XPE  ((size_t)15 * BH_)
#define HPE  ((size_t)32 * BH_)
#define NT   32                         // K-steps (BK=64)

struct Stage { int node[8]; int par[8]; int layer[8]; int cnt; };

__device__ __forceinline__ u16 bf16_rn(float x) {
    union { float f; u32 u; } v; v.f = x;
    return (u16)((v.u + 0x7FFFu + ((v.u >> 16) & 1u)) >> 16);
}
__device__ __forceinline__ float sigf(float x) {
    return __builtin_amdgcn_rcpf(1.0f + __expf(-x));
}
__device__ __forceinline__ float tanh_f(float x) {
    return 1.0f - 2.0f * __builtin_amdgcn_rcpf(1.0f + __expf(2.0f * x));
}

// ---------------------------------------------------------------------------
// Pack W into MFMA-B fragment order, bf16. Chunk w = ((layer*4+gate)*32+cg)*128+k16;
// lane l -> W[gate*1024+cg*32+(l&31)][k16*16+(l>>5)*8+e].
// ---------------------------------------------------------------------------
__global__ __launch_bounds__(256)
void pack_weights(const float* __restrict__ Wih, const float* __restrict__ Whh,
                  u16* __restrict__ wp)
{
    const int gt = blockIdx.x * 256 + threadIdx.x;
    const int w = gt >> 6, lane = gt & 63;
    const int k16 = w & 127, cg = (w >> 7) & 31, gate = (w >> 12) & 3, layer = w >> 14;
    const int row = gate * 1024 + cg * 32 + (lane & 31);
    const int k = k16 * 16 + (lane >> 5) * 8;
    const float* src = (k < 1024)
        ? Wih + ((size_t)layer * 4096 + row) * 1024 + k
        : Whh + ((size_t)layer * 4096 + row) * 1024 + (k - 1024);
    const float4 v0 = *(const float4*)src;
    const float4 v1 = *(const float4*)(src + 4);
    const float a[8] = {v0.x, v0.y, v0.z, v0.w, v1.x, v1.y, v1.z, v1.w};
    union { u16 s[8]; uint4 v; } hi;
    #pragma unroll
    for (int e = 0; e < 8; ++e) hi.s[e] = bf16_rn(a[e]);
    *(uint4*)(wp + (size_t)w * 512 + (size_t)lane * 8) = hi.v;
}

__global__ __launch_bounds__(256)
void pack_x(const float* __restrict__ input, const float* __restrict__ bridge,
            u16* __restrict__ xp)
{
    const int gt = blockIdx.x * 256 + threadIdx.x;
    const int w = gt >> 6, lane = gt & 63;
    const int k16 = w & 63, btile = (w >> 6) & 7, n1 = w >> 9;
    const int b = btile * 32 + (lane & 31);
    const int k = k16 * 16 + (lane >> 5) * 8;
    const float* src = (k < 512)
        ? input  + ((size_t)n1 * 256 + b) * 512 + k
        : bridge + ((size_t)n1 * 256 + b) * 512 + (k - 512);
    const float4 v0 = *(const float4*)src;
    const float4 v1 = *(const float4*)(src + 4);
    const float a[8] = {v0.x, v0.y, v0.z, v0.w, v1.x, v1.y, v1.z, v1.w};
    union { u16 s[8]; uint4 v; } hi;
    #pragma unroll
    for (int e = 0; e < 8; ++e) hi.s[e] = bf16_rn(a[e]);
    *(uint4*)(xp + (size_t)w * 512 + (size_t)lane * 8) = hi.v;
}

__global__ __launch_bounds__(256)
void bias_sum_k(const float* __restrict__ bih, const float* __restrict__ bhh,
                float* __restrict__ bs)
{
    const int i = blockIdx.x * 256 + threadIdx.x;
    if (i < 8192) bs[i] = bih[i] + bhh[i];
}

// ---------------------------------------------------------------------------
// Fused cell, true counted-vmcnt pipeline. Block = 512 thr (8 waves).
// Block tile: 256 batch x 64 hh x 4 gates (256 N). Wave (bg=wv&3, cg=wv>>2):
// 64 batch x (4 gates x 32 hh) -> acc[2][4] fx16.
// LDS (160 KB exactly): W ring-3 x 32 KB + A ring-2 x 32 KB, all staged via
// global_load_lds (4 instr/thread each; no register global loads in loop).
// Per step: issue A(t+1) then W(t+2)  ->  FIFO stream [W(t),A(t),W(t+1)];
// wait vmcnt(4) retires exactly {W(t),A(t)}, leaves W(t+1) in flight.
// One raw s_barrier per step publishes LDS; slot overwrites are protected
// because barrier(t) follows compute(t-1) in every wave's program order.
// blocks/cell = 16 (hh blocks); grid = cnt*16.
// ---------------------------------------------------------------------------
__global__ __launch_bounds__(512, 2)
void cell_fused(const u16* __restrict__ wp, const u16* __restrict__ xp,
                u16* __restrict__ hp, float* __restrict__ c_buf,
                const float* __restrict__ bsum, float* __restrict__ out,
                Stage st)
{
    __shared__ u16 SM[81920];           // 160 KB
    u16* Wr = SM;                        // 3 x 16384 elems (32 KB each)
    u16* Ar = SM + 49152;                // 2 x 16384 elems

    const int bid  = blockIdx.x;
    const int cell = bid >> 4;
    const int n    = bid & 15;           // hh block (64 hh per block)
    const int node = st.node[cell], par = st.par[cell], layer = st.layer[cell];
    const int tid = threadIdx.x, wv = tid >> 6, lane = tid & 63;
    const int bg = wv & 3;               // batch group (64 rows)
    const int cg = wv >> 2;              // hh subgroup (32 cols)

    // A segment bases (seg0 = K 0..1023, seg1 = K 1024..2047)
    const u16 *A0, *A1;
    if (layer == 0) {
        A0 = xp + (size_t)(node - 1) * BH_;
        A1 = hp + (size_t)(par * 2 + 0) * BH_;
    } else {
        A0 = hp + (size_t)(node * 2 + 0) * BH_;
        A1 = hp + (size_t)(par * 2 + 1) * BH_;
    }

    const int tq = tid >> 8;             // 0/1
    const int tr = tid & 255;            // 0..255

    // W: per instr i: cg_local = i>>1, gate = ((i&1)<<1)|tq. LDS region
    // (cg_local*4+g)*2048 emerges from linear dest i*4096 + tid*8.
    size_t wsrc[4];
    #pragma unroll
    for (int i = 0; i < 4; ++i) {
        const int cgc = n * 2 + (i >> 1);
        const int g   = ((i & 1) << 1) | tq;
        wsrc[i] = (size_t)((layer * 4 + g) * 32 + cgc) * 65536 + (size_t)tr * 8;
    }

    #define STAGE_W(T, S) do {                                                 \
        _Pragma("unroll")                                                      \
        for (int i_ = 0; i_ < 4; ++i_) {                                       \
            __builtin_amdgcn_global_load_lds(                                  \
                (const __attribute__((address_space(1))) void*)                \
                    (wp + wsrc[i_] + (size_t)(T) * 2048),                      \
                (__attribute__((address_space(3))) void*)                      \
                    (Wr + (S) * 16384 + i_ * 4096 + tid * 8),                  \
                16, 0, 0);                                                     \
        }                                                                      \
    } while (0)

    // A: per instr i: btile = i*2 + tq; LDS layout bt*2048 + kslot*512 + e.
    #define STAGE_A(T, S) do {                                                 \
        const u16* As_ = ((T) < 16) ? A0 : A1;                                 \
        const size_t ko_ = (size_t)((T) & 15) * 2048 + (size_t)tr * 8;         \
        _Pragma("unroll")                                                      \
        for (int i_ = 0; i_ < 4; ++i_) {                                       \
            const int bt_ = i_ * 2 + tq;                                       \
            __builtin_amdgcn_global_load_lds(                                  \
                (const __attribute__((address_space(1))) void*)                \
                    (As_ + (size_t)bt_ * 32768 + ko_),                         \
                (__attribute__((address_space(3))) void*)                      \
                    (Ar + (S) * 16384 + i_ * 4096 + tid * 8),                  \
                16, 0, 0);                                                     \
        }                                                                      \
    } while (0)

    #define COMPUTE(SW, SA) do {                                               \
        _Pragma("unroll")                                                      \
        for (int kk_ = 0; kk_ < 4; ++kk_) {                                    \
            const s16x8 a0_ = *(const s16x8*)                                  \
                (Ar + (SA) * 16384 + (bg * 2) * 2048 + kk_ * 512 + lane * 8);  \
            const s16x8 a1_ = *(const s16x8*)                                  \
                (Ar + (SA) * 16384 + (bg * 2 + 1) * 2048 + kk_ * 512 + lane * 8);\
            _Pragma("unroll")                                                  \
            for (int g_ = 0; g_ < 4; ++g_) {                                   \
                const s16x8 w_ = *(const s16x8*)                               \
                    (Wr + (SW) * 16384 + (cg * 4 + g_) * 2048 + kk_ * 512      \
                     + lane * 8);                                              \
                acc[0][g_] = __builtin_amdgcn_mfma_f32_32x32x16_bf16(          \
                    a0_, w_, acc[0][g_], 0, 0, 0);                             \
                acc[1][g_] = __builtin_amdgcn_mfma_f32_32x32x16_bf16(          \
                    a1_, w_, acc[1][g_], 0, 0, 0);                             \
            }                                                                  \
        }                                                                      \
    } while (0)

    fx16 acc[2][4];
    #pragma unroll
    for (int q = 0; q < 2; ++q)
        #pragma unroll
        for (int g = 0; g < 4; ++g)
            #pragma unroll
            for (int r = 0; r < 16; ++r) acc[q][g][r] = 0.0f;

    // prologue: stream [W0, A0, W1] = 12 outstanding
    STAGE_W(0, 0);
    STAGE_A(0, 0);
    STAGE_W(1, 1);

    #pragma unroll 1
    for (int t = 0; t < NT; ++t) {
        // retire exactly {W(t), A(t)}; W(t+1) stays in flight
        asm volatile("s_waitcnt vmcnt(4)" ::: "memory");
        __builtin_amdgcn_s_barrier();
        const int ta = (t + 1 < NT) ? t + 1 : NT - 1;      // dummy at tail
        const int tw = (t + 2 < NT) ? t + 2 : NT - 1;
        STAGE_A(ta, (t + 1) & 1);
        STAGE_W(tw, (t + 2) % 3);
        COMPUTE(t % 3, t & 1);
    }
    __syncthreads();   // drain tail dummies before LDS reuse

    // ---- fused gates epilogue (C/D: col=lane&31, row=(r&3)+8*(r>>2)+4*(lane>>5))
    const int col  = lane & 31;
    const int colg = n * 64 + cg * 32 + col;
    float bs4[4];
    #pragma unroll
    for (int g = 0; g < 4; ++g)
        bs4[g] = bsum[layer * 4096 + g * 1024 + colg];

    const float* cpar_base = c_buf + (size_t)(par * 2 + layer) * BH_ + colg;
    float*       cnew_base = c_buf + (size_t)(node * 2 + layer) * BH_ + colg;
    float*       out_base  = out + (size_t)(node - 1) * BH_ + colg;

    u32* hb = (u32*)(&SM[0]);   // 16 regions x 32x33 u32 = 67.6 KB

    #pragma unroll
    for (int q = 0; q < 2; ++q) {
        const int bt = bg * 2 + q;
        u32* hq = hb + (wv * 2 + q) * 1056;
        #pragma unroll
        for (int r = 0; r < 16; ++r) {
            const int rl = 4 * (lane >> 5) + (r & 3) + 8 * (r >> 2);
            const size_t row = (size_t)(bt * 32 + rl) * 1024;
            const float gi = acc[q][0][r] + bs4[0];
            const float gf = acc[q][1][r] + bs4[1];
            const float gg = acc[q][2][r] + bs4[2];
            const float go = acc[q][3][r] + bs4[3];
            const float cp = cpar_base[row];
            const float cn = sigf(gf) * cp + sigf(gi) * tanh_f(gg);
            const float hn = sigf(go) * tanh_f(cn);
            cnew_base[row] = cn;
            if (layer == 1) out_base[row] = hn;
            hq[rl * 33 + col] = (u32)bf16_rn(hn);
        }
    }

    // ---- transpose h (wave-local scratch) into packed A-frag chunks
    #pragma unroll
    for (int q = 0; q < 2; ++q) {
        const int bt = bg * 2 + q;
        const u32* hq = hb + (wv * 2 + q) * 1056;
        #pragma unroll
        for (int h2 = 0; h2 < 2; ++h2) {
            const int k16g = n * 4 + cg * 2 + h2;
            union { u16 s[8]; uint4 v; } pk;
            #pragma unroll
            for (int e = 0; e < 8; ++e)
                pk.s[e] = (u16)hq[(lane & 31) * 33 + h2 * 16 + (lane >> 5) * 8 + e];
            *(uint4*)(hp + (size_t)(node * 2 + layer) * BH_
                      + ((size_t)bt * 64 + k16g) * 512 + lane * 8) = pk.v;
        }
    }
    #undef STAGE_W
    #undef STAGE_A
    #undef COMPUTE
}

// ---------------------------------------------------------------------------
extern "C" void kernel_launch(void* const* d_in, const int* in_sizes, int n_in,
                              void* d_out, int out_size, void* d_ws, size_t ws_size,
                              hipStream_t stream)
{
    const float* input  = (const float*)d_in[0];
    const float* bridge = (const float*)d_in[1];
    const float* Wih    = (const float*)d_in[2];
    const float* Whh    = (const float*)d_in[3];
    const float* bih    = (const float*)d_in[4];
    const float* bhh    = (const float*)d_in[5];
    float* out = (float*)d_out;

    u16* wp = (u16*)d_ws;
    u16* xp = wp + WPE;
    u16* hp = xp + XPE;
    float* c_buf = (float*)(hp + HPE);
    float* bsum  = c_buf + HPE;

    hipMemsetAsync(hp, 0, (size_t)2 * BH_ * sizeof(u16), stream);
    hipMemsetAsync(c_buf, 0, (size_t)2 * BH_ * sizeof(float), stream);

    bias_sum_k<<<32, 256, 0, stream>>>(bih, bhh, bsum);
    pack_weights<<<8192, 256, 0, stream>>>(Wih, Whh, wp);
    pack_x<<<1920, 256, 0, stream>>>(input, bridge, xp);

    // Wavefront schedule: stage T = cells (node,layer) with depth(node)+layer==T
    static const Stage stages[7] = {
        { {1},                      {0},                      {0},                      1 },
        { {1,2,5,8},                {0,1,1,1},                {1,0,0,0},                4 },
        { {2,5,8,3,6,9,12},         {1,1,1,2,5,8,8},          {1,1,1,0,0,0,0},          7 },
        { {3,6,9,12,4,7,10,13},     {2,5,8,8,3,6,9,12},       {1,1,1,1,0,0,0,0},        8 },
        { {4,7,10,13,11,14},        {3,6,9,12,10,13},         {1,1,1,1,0,0},            6 },
        { {11,14,15},               {10,13,14},               {1,1,0},                  3 },
        { {15},                     {14},                     {1},                      1 },
    };

    for (int s = 0; s < 7; ++s) {
        cell_fused<<<dim3(stages[s].cnt * 16), 512, 0, stream>>>(
            wp, xp, hp, c_buf, bsum, out, stages[s]);
    }
}

// Round 8
// 297.500 us; speedup vs baseline: 1.7348x; 1.5197x over previous
//
#include <hip/hip_runtime.h>
#include <stdint.h>

typedef unsigned short u16;
typedef uint32_t u32;
typedef short s16x8 __attribute__((ext_vector_type(8)));
typedef float fx16 __attribute__((ext_vector_type(16)));

#define B_   256
#define H_   1024
#define BH_  (B_ * H_)                  // 262144
#define WPE  ((size_t)2 * 4096 * 2048)  // W pack elems
#define XPE  ((size_t)15 * BH_)
#define HPE  ((size_t)32 * BH_)
#define NT   32                         // K-steps (BK=64)

struct Stage { int node[8]; int par[8]; int layer[8]; int cnt; };

__device__ __forceinline__ u16 bf16_rn(float x) {
    union { float f; u32 u; } v; v.f = x;
    return (u16)((v.u + 0x7FFFu + ((v.u >> 16) & 1u)) >> 16);
}
__device__ __forceinline__ float sigf(float x) {
    return __builtin_amdgcn_rcpf(1.0f + __expf(-x));
}
__device__ __forceinline__ float tanh_f(float x) {
    return 1.0f - 2.0f * __builtin_amdgcn_rcpf(1.0f + __expf(2.0f * x));
}

// ---------------------------------------------------------------------------
// Pack W into MFMA-B fragment order, bf16. Chunk w = ((layer*4+gate)*32+cg)*128+k16;
// lane l -> W[gate*1024+cg*32+(l&31)][k16*16+(l>>5)*8+e].
// ---------------------------------------------------------------------------
__global__ __launch_bounds__(256)
void pack_weights(const float* __restrict__ Wih, const float* __restrict__ Whh,
                  u16* __restrict__ wp)
{
    const int gt = blockIdx.x * 256 + threadIdx.x;
    const int w = gt >> 6, lane = gt & 63;
    const int k16 = w & 127, cg = (w >> 7) & 31, gate = (w >> 12) & 3, layer = w >> 14;
    const int row = gate * 1024 + cg * 32 + (lane & 31);
    const int k = k16 * 16 + (lane >> 5) * 8;
    const float* src = (k < 1024)
        ? Wih + ((size_t)layer * 4096 + row) * 1024 + k
        : Whh + ((size_t)layer * 4096 + row) * 1024 + (k - 1024);
    const float4 v0 = *(const float4*)src;
    const float4 v1 = *(const float4*)(src + 4);
    const float a[8] = {v0.x, v0.y, v0.z, v0.w, v1.x, v1.y, v1.z, v1.w};
    union { u16 s[8]; uint4 v; } hi;
    #pragma unroll
    for (int e = 0; e < 8; ++e) hi.s[e] = bf16_rn(a[e]);
    *(uint4*)(wp + (size_t)w * 512 + (size_t)lane * 8) = hi.v;
}

__global__ __launch_bounds__(256)
void pack_x(const float* __restrict__ input, const float* __restrict__ bridge,
            u16* __restrict__ xp)
{
    const int gt = blockIdx.x * 256 + threadIdx.x;
    const int w = gt >> 6, lane = gt & 63;
    const int k16 = w & 63, btile = (w >> 6) & 7, n1 = w >> 9;
    const int b = btile * 32 + (lane & 31);
    const int k = k16 * 16 + (lane >> 5) * 8;
    const float* src = (k < 512)
        ? input  + ((size_t)n1 * 256 + b) * 512 + k
        : bridge + ((size_t)n1 * 256 + b) * 512 + (k - 512);
    const float4 v0 = *(const float4*)src;
    const float4 v1 = *(const float4*)(src + 4);
    const float a[8] = {v0.x, v0.y, v0.z, v0.w, v1.x, v1.y, v1.z, v1.w};
    union { u16 s[8]; uint4 v; } hi;
    #pragma unroll
    for (int e = 0; e < 8; ++e) hi.s[e] = bf16_rn(a[e]);
    *(uint4*)(xp + (size_t)w * 512 + (size_t)lane * 8) = hi.v;
}

__global__ __launch_bounds__(256)
void bias_sum_k(const float* __restrict__ bih, const float* __restrict__ bhh,
                float* __restrict__ bs)
{
    const int i = blockIdx.x * 256 + threadIdx.x;
    if (i < 8192) bs[i] = bih[i] + bhh[i];
}

// ---------------------------------------------------------------------------
// Fused cell, m97-regime. Block = 256 thr (4 waves), tile M=128 x N=128
// (4 gates x 32 hh). Wave (mw,nw) 2x2 -> 64 rows x 64 cols, acc 2x2 fx16.
// K-loop: BK=64, 32 steps, SINGLE-buffer 32 KB staged via global_load_lds
// (8 instr/thread/step), plain __syncthreads pair -- latency hidden by
// 3-4 resident blocks/CU (LDS 37 KB, launch_bounds(256,3)), m114-style
// cross-block overlap. 64 blocks/cell; XCD swizzle keeps an hhblk group
// (fixed W slice) on one XCD across cells/stages.
// ---------------------------------------------------------------------------
__global__ __launch_bounds__(256, 3)
void cell_fused(const u16* __restrict__ wp, const u16* __restrict__ xp,
                u16* __restrict__ hp, float* __restrict__ c_buf,
                const float* __restrict__ bsum, float* __restrict__ out,
                Stage st)
{
    __shared__ __align__(16) char SMEM[37376];
    u16*   AL   = (u16*)SMEM;            // [btl(4)][kk(4)][512] = 16 KB
    u16*   WL   = AL + 8192;             // [g(4)][kk(4)][512]   = 16 KB
    float* gbuf = (float*)SMEM;          // [64][129] f32 = 33024 B (epilogue)
    u16*   tbuf = (u16*)(SMEM + 33024);  // [64][33] u16 = 4224 B (epilogue)

    const int u = blockIdx.x;
    const int hhblk = 4 * (u & 7) + ((u >> 3) & 3);   // 0..31, XCD-stable
    const int v = u >> 5;
    const int cnt = st.cnt;
    const int cell = v % cnt;
    const int mblk = v / cnt;                          // 0..1
    const int node = st.node[cell], par = st.par[cell], layer = st.layer[cell];
    const int tid = threadIdx.x, wv = tid >> 6, lane = tid & 63;
    const int mw = wv >> 1, nw = wv & 1;
    const int tg = tid >> 6;                           // 0..3 (staging kk group)
    const int tl8 = (tid & 63) * 8;

    // A segment bases (seg0 = K 0..1023, seg1 = K 1024..2047)
    const u16 *A0, *A1;
    if (layer == 0) {
        A0 = xp + (size_t)(node - 1) * BH_;
        A1 = hp + (size_t)(par * 2 + 0) * BH_;
    } else {
        A0 = hp + (size_t)(node * 2 + 0) * BH_;
        A1 = hp + (size_t)(par * 2 + 1) * BH_;
    }
    // W base: chunk ((layer*4+g)*32+hhblk)*128 + k16  (k16 = 0..127 full K)
    size_t wsrc[4];
    #pragma unroll
    for (int g = 0; g < 4; ++g)
        wsrc[g] = ((size_t)((layer * 4 + g) * 32 + hhblk) * 128 + tg) * 512
                + (size_t)tl8;

    fx16 acc[2][2];
    #pragma unroll
    for (int m = 0; m < 2; ++m)
        #pragma unroll
        for (int n = 0; n < 2; ++n)
            #pragma unroll
            for (int r = 0; r < 16; ++r) acc[m][n][r] = 0.0f;

    #pragma unroll 1
    for (int t = 0; t < NT; ++t) {
        // ---- stage: A 16KB (4 instr: btl=i, kk=tg) + W 16KB (4 instr: g=i)
        const u16* As = (t < 16) ? A0 : A1;
        const int k16 = (t & 15) * 4 + tg;           // A k16 within segment
        #pragma unroll
        for (int i = 0; i < 4; ++i) {
            __builtin_amdgcn_global_load_lds(
                (const __attribute__((address_space(1))) void*)
                    (As + ((size_t)(mblk * 4 + i) * 64 + k16) * 512 + tl8),
                (__attribute__((address_space(3))) void*)
                    (AL + (i * 4 + tg) * 512 + tl8),
                16, 0, 0);
        }
        #pragma unroll
        for (int i = 0; i < 4; ++i) {
            __builtin_amdgcn_global_load_lds(
                (const __attribute__((address_space(1))) void*)
                    (wp + wsrc[i] + (size_t)t * 4 * 512),
                (__attribute__((address_space(3))) void*)
                    (WL + (i * 4 + tg) * 512 + tl8),
                16, 0, 0);
        }
        __syncthreads();
        // ---- compute: 16 ds_read_b128 + 16 MFMA per wave
        #pragma unroll
        for (int kk = 0; kk < 4; ++kk) {
            s16x8 a[2], w[2];
            #pragma unroll
            for (int m = 0; m < 2; ++m)
                a[m] = *(const s16x8*)(AL + ((mw * 2 + m) * 4 + kk) * 512 + lane * 8);
            #pragma unroll
            for (int n = 0; n < 2; ++n)
                w[n] = *(const s16x8*)(WL + ((nw * 2 + n) * 4 + kk) * 512 + lane * 8);
            #pragma unroll
            for (int m = 0; m < 2; ++m)
                #pragma unroll
                for (int n = 0; n < 2; ++n)
                    acc[m][n] = __builtin_amdgcn_mfma_f32_32x32x16_bf16(
                        a[m], w[n], acc[m][n], 0, 0, 0);
        }
        __syncthreads();
    }

    // ---- fused epilogue, two row-passes (p = mw of producing waves)
    const int hhl  = tid & 31;
    const int colg = hhblk * 32 + hhl;
    float bs4[4];
    #pragma unroll
    for (int g = 0; g < 4; ++g)
        bs4[g] = bsum[layer * 4096 + g * 1024 + colg];

    const float* cpar = c_buf + (size_t)(par * 2 + layer) * BH_ + colg;
    float*       cnew = c_buf + (size_t)(node * 2 + layer) * BH_ + colg;
    float*       outp = out + (size_t)(node - 1) * BH_ + colg;
    u16*         hpn  = hp + (size_t)(node * 2 + layer) * BH_;

    #pragma unroll
    for (int p = 0; p < 2; ++p) {
        __syncthreads();
        if (mw == p) {
            // C/D layout: col = lane&31, row = (r&3)+8*(r>>2)+4*(lane>>5)
            #pragma unroll
            for (int m = 0; m < 2; ++m) {
                #pragma unroll
                for (int n = 0; n < 2; ++n) {
                    const int col = (nw * 2 + n) * 32 + (lane & 31);
                    #pragma unroll
                    for (int r = 0; r < 16; ++r) {
                        const int row_l = m * 32 + 4 * (lane >> 5)
                                        + (r & 3) + 8 * (r >> 2);
                        gbuf[row_l * 129 + col] = acc[m][n][r];
                    }
                }
            }
        }
        __syncthreads();
        // gate math: 8 rows/thread-group x 32 hh
        #pragma unroll
        for (int e = 0; e < 8; ++e) {
            const int row_l = e * 8 + (tid >> 5);
            const size_t grow = (size_t)(mblk * 128 + p * 64 + row_l) * 1024;
            const float gi = gbuf[row_l * 129 + 0  * 32 + hhl] + bs4[0];
            const float gf = gbuf[row_l * 129 + 1  * 32 + hhl] + bs4[1];
            const float gg = gbuf[row_l * 129 + 2  * 32 + hhl] + bs4[2];
            const float go = gbuf[row_l * 129 + 3  * 32 + hhl] + bs4[3];
            const float cp = cpar[grow];
            const float cn = sigf(gf) * cp + sigf(gi) * tanh_f(gg);
            const float hn = sigf(go) * tanh_f(cn);
            cnew[grow] = cn;
            if (layer == 1) outp[grow] = hn;
            tbuf[row_l * 33 + hhl] = bf16_rn(hn);
        }
        __syncthreads();
        // pack h: 4 chunks (j = btl-in-pass, q = k16 half), one per wave
        {
            const int j = wv >> 1, q = wv & 1;
            const int bt   = mblk * 4 + p * 2 + j;
            const int k16h = hhblk * 2 + q;
            union { u16 s[8]; uint4 v; } pk;
            #pragma unroll
            for (int e = 0; e < 8; ++e)
                pk.s[e] = tbuf[(j * 32 + (lane & 31)) * 33
                               + q * 16 + (lane >> 5) * 8 + e];
            *(uint4*)(hpn + ((size_t)bt * 64 + k16h) * 512 + lane * 8) = pk.v;
        }
    }
}

// ---------------------------------------------------------------------------
extern "C" void kernel_launch(void* const* d_in, const int* in_sizes, int n_in,
                              void* d_out, int out_size, void* d_ws, size_t ws_size,
                              hipStream_t stream)
{
    const float* input  = (const float*)d_in[0];
    const float* bridge = (const float*)d_in[1];
    const float* Wih    = (const float*)d_in[2];
    const float* Whh    = (const float*)d_in[3];
    const float* bih    = (const float*)d_in[4];
    const float* bhh    = (const float*)d_in[5];
    float* out = (float*)d_out;

    u16* wp = (u16*)d_ws;
    u16* xp = wp + WPE;
    u16* hp = xp + XPE;
    float* c_buf = (float*)(hp + HPE);
    float* bsum  = c_buf + HPE;

    hipMemsetAsync(hp, 0, (size_t)2 * BH_ * sizeof(u16), stream);
    hipMemsetAsync(c_buf, 0, (size_t)2 * BH_ * sizeof(float), stream);

    bias_sum_k<<<32, 256, 0, stream>>>(bih, bhh, bsum);
    pack_weights<<<8192, 256, 0, stream>>>(Wih, Whh, wp);
    pack_x<<<1920, 256, 0, stream>>>(input, bridge, xp);

    // Wavefront schedule: stage T = cells (node,layer) with depth(node)+layer==T
    static const Stage stages[7] = {
        { {1},                      {0},                      {0},                      1 },
        { {1,2,5,8},                {0,1,1,1},                {1,0,0,0},                4 },
        { {2,5,8,3,6,9,12},         {1,1,1,2,5,8,8},          {1,1,1,0,0,0,0},          7 },
        { {3,6,9,12,4,7,10,13},     {2,5,8,8,3,6,9,12},       {1,1,1,1,0,0,0,0},        8 },
        { {4,7,10,13,11,14},        {3,6,9,12,10,13},         {1,1,1,1,0,0},            6 },
        { {11,14,15},               {10,13,14},               {1,1,0},                  3 },
        { {15},                     {14},                     {1},                      1 },
    };

    for (int s = 0; s < 7; ++s) {
        cell_fused<<<dim3(stages[s].cnt * 64), 256, 0, stream>>>(
            wp, xp, hp, c_buf, bsum, out, stages[s]);
    }
}